// Round 2
// baseline (504.583 us; speedup 1.0000x reference)
//
#include <hip/hip_runtime.h>
#include <hip/hip_bf16.h>

// PropNet on MI355X — fp32 inputs/outputs (per reference), bf16 MFMA compute.
// B=4, N=1024, E=8192, NF_IN=32, H=128, NF_OUT=3, pstep=2 (fixed input).
//
// Pipeline:
//  1) k_wprep  : fp32 [K,128] weights -> bf16 MFMA B-fragment order.
//  2) k_extract: scan fp32 one-hot Rr/Rs rows -> recv/send indices
//                (wave-per-row, float4 loads, early exit, defensive default).
//  3) k_mfma   : generic fused linear layer. A = up to 3 concat segments
//                (fp32 or bf16 source, optional row-gather), 16x16x32 bf16
//                MFMA, epilogue bias+resid+ReLU; out = bf16 / fp32 / fused
//                atomic scatter-add into fp32 agg.
//  4) k_final  : [4096,128] @ [128,3] + bias (no ReLU) -> fp32 d_out.

typedef unsigned short u16;
typedef __attribute__((ext_vector_type(8))) __bf16 bf16x8;
typedef __attribute__((ext_vector_type(4))) float f32x4;

#define N_    1024
#define BN    4096      // B*N
#define BE    32768     // B*E
#define LOG_E 13
#define H_    128

__device__ __forceinline__ u16 f2bf(float f) {
    __bf16 h = (__bf16)f;
    return __builtin_bit_cast(u16, h);
}

// ---------------------------------------------------------------------------
// Weight permutation into bf16 B-fragment order:
// dst[((c*8+nt)*64+lane)*8+j] = bf16(W[c*32 + (lane>>4)*8 + j][nt*16 + (lane&15)])
// ---------------------------------------------------------------------------
struct WDesc { const float* src; u16* dst; int K; };
struct WPack { WDesc d[10]; };

__global__ __launch_bounds__(256) void k_wprep(WPack P) {
    WDesc d = P.d[blockIdx.y];
    int i = blockIdx.x * 256 + threadIdx.x;
    if (i >= d.K * 128) return;
    int j    = i & 7;
    int lane = (i >> 3) & 63;
    int nt   = (i >> 9) & 7;
    int c    = i >> 12;
    int k = c * 32 + (lane >> 4) * 8 + j;
    int n = nt * 16 + (lane & 15);
    d.dst[i] = f2bf(d.src[k * 128 + n]);
}

// ---------------------------------------------------------------------------
// fp32 one-hot -> index. One wave per row; early exit; defensive default 0.
// ---------------------------------------------------------------------------
__global__ __launch_bounds__(256) void k_extract(const float* __restrict__ Rr,
                                                 const float* __restrict__ Rs,
                                                 int* __restrict__ recv,
                                                 int* __restrict__ send) {
    int wave = threadIdx.x >> 6, lane = threadIdx.x & 63;
    int g = blockIdx.x * 4 + wave;           // < 2*BE
    const float* src;
    int* dst;
    if (g < BE) { src = Rr + (size_t)g * N_;        dst = recv + g; }
    else        { src = Rs + (size_t)(g - BE) * N_; dst = send + (g - BE); }
    int idx = 0;
    bool done = false;
    #pragma unroll
    for (int it = 0; it < 4; ++it) {
        if (!done) {
            int base = it * 256 + lane * 4;
            float4 v = *(const float4*)(src + base);
            int found = -1;
            if      (v.x != 0.f) found = base;
            else if (v.y != 0.f) found = base + 1;
            else if (v.z != 0.f) found = base + 2;
            else if (v.w != 0.f) found = base + 3;
            unsigned long long m = __ballot(found >= 0);
            if (m) {
                int sl = __ffsll((long long)m) - 1;
                idx = __shfl(found, sl, 64);
                done = true;
            }
        }
    }
    if (lane == 0) *dst = idx;
}

// ---------------------------------------------------------------------------
// Zero fp32 buffer (float4 granularity).
// ---------------------------------------------------------------------------
__global__ __launch_bounds__(256) void k_zero(float* __restrict__ p, int n4) {
    int i = blockIdx.x * 256 + threadIdx.x;
    if (i < n4) ((float4*)p)[i] = make_float4(0.f, 0.f, 0.f, 0.f);
}

// ---------------------------------------------------------------------------
// Generic MFMA linear layer.
// Block = 256 threads = 4 waves; each wave: 16 rows x 128 cols.
// Segment widths are multiples of 32 -> per-chunk segment choice is uniform.
// ---------------------------------------------------------------------------
struct SegD { const void* p; const int* idx; int f32; int w; };

__global__ __launch_bounds__(256) void k_mfma(
    SegD s0, SegD s1, SegD s2, int nseg, int KC,
    const u16* __restrict__ Wf, const float* __restrict__ bias,
    const float* __restrict__ resid,
    int mode,                 // 0: store bf16; 1: atomicAdd fp32 agg via scidx; 2: store fp32
    void* __restrict__ outp, const int* __restrict__ scidx)
{
    int wave = threadIdx.x >> 6, lane = threadIdx.x & 63;
    int m = lane & 15, quad = lane >> 4;
    int row16 = blockIdx.x * 64 + wave * 16;
    int row = row16 + m;
    int b = row >> LOG_E;

    // hoist per-segment gathered row index
    long r0 = (nseg > 0 && s0.idx) ? ((long)b * N_ + s0.idx[row]) : (long)row;
    long r1 = (nseg > 1 && s1.idx) ? ((long)b * N_ + s1.idx[row]) : (long)row;
    long r2s = (nseg > 2 && s2.idx) ? ((long)b * N_ + s2.idx[row]) : (long)row;
    int w0 = s0.w, w01 = s0.w + s1.w;

    f32x4 acc[8];
    #pragma unroll
    for (int t = 0; t < 8; ++t) acc[t] = (f32x4){0.f, 0.f, 0.f, 0.f};

    for (int c = 0; c < KC; ++c) {
        int kk = c * 32 + quad * 8;
        SegD s = s0; long r = r0; int base = 0;
        if (nseg > 1 && kk >= w0) {
            s = s1; r = r1; base = w0;
            if (nseg > 2 && kk >= w01) { s = s2; r = r2s; base = w01; }
        }
        int off = kk - base;

        bf16x8 a;
        if (s.f32) {
            const float* pf = (const float*)s.p + r * s.w + off;
            float4 f0 = *(const float4*)pf;
            float4 f1 = *(const float4*)(pf + 4);
            a[0] = (__bf16)f0.x; a[1] = (__bf16)f0.y;
            a[2] = (__bf16)f0.z; a[3] = (__bf16)f0.w;
            a[4] = (__bf16)f1.x; a[5] = (__bf16)f1.y;
            a[6] = (__bf16)f1.z; a[7] = (__bf16)f1.w;
        } else {
            a = *(const bf16x8*)((const u16*)s.p + r * s.w + off);
        }

        const u16* wp = Wf + ((size_t)c * 8) * 64 * 8;
        #pragma unroll
        for (int nt = 0; nt < 8; ++nt) {
            bf16x8 bw = *(const bf16x8*)(wp + (size_t)(nt * 64 + lane) * 8);
            acc[nt] = __builtin_amdgcn_mfma_f32_16x16x32_bf16(a, bw, acc[nt], 0, 0, 0);
        }
    }

    // epilogue: D[row=quad*4+i][col=nt*16+m]  (m89-verified C/D layout)
    #pragma unroll
    for (int nt = 0; nt < 8; ++nt) {
        int col = nt * 16 + m;
        float bv = bias[col];
        #pragma unroll
        for (int i = 0; i < 4; ++i) {
            int r = row16 + quad * 4 + i;
            float v = acc[nt][i] + bv;
            if (resid) v += resid[(size_t)r * H_ + col];
            v = fmaxf(v, 0.f);   // all k_mfma layers here end in ReLU
            if (mode == 0) {
                ((u16*)outp)[(size_t)r * H_ + col] = f2bf(v);
            } else if (mode == 2) {
                ((float*)outp)[(size_t)r * H_ + col] = v;
            } else {
                int b2 = r >> LOG_E;
                atomicAdd((float*)outp + (((size_t)b2 * N_ + scidx[r]) * H_ + col), v);
            }
        }
    }
}

// ---------------------------------------------------------------------------
// Final layer: p2[4096,128](bf16) @ ppW2[128,3](fp32) + ppb2 -> fp32 out.
// ---------------------------------------------------------------------------
__global__ __launch_bounds__(256) void k_final(const u16* __restrict__ p2,
                                               const float* __restrict__ W,
                                               const float* __restrict__ bias,
                                               float* __restrict__ out) {
    int wave = threadIdx.x >> 6, lane = threadIdx.x & 63;
    int row = blockIdx.x * 4 + wave;
    if (row >= BN) return;
    float a0 = __uint_as_float(((unsigned)p2[(size_t)row * 128 + lane]) << 16);
    float a1 = __uint_as_float(((unsigned)p2[(size_t)row * 128 + 64 + lane]) << 16);
    float s0 = a0 * W[lane * 3 + 0] + a1 * W[(lane + 64) * 3 + 0];
    float s1 = a0 * W[lane * 3 + 1] + a1 * W[(lane + 64) * 3 + 1];
    float s2 = a0 * W[lane * 3 + 2] + a1 * W[(lane + 64) * 3 + 2];
    #pragma unroll
    for (int o = 32; o > 0; o >>= 1) {
        s0 += __shfl_xor(s0, o, 64);
        s1 += __shfl_xor(s1, o, 64);
        s2 += __shfl_xor(s2, o, 64);
    }
    if (lane == 0) {
        out[row * 3 + 0] = s0 + bias[0];
        out[row * 3 + 1] = s1 + bias[1];
        out[row * 3 + 2] = s2 + bias[2];
    }
}

// ---------------------------------------------------------------------------
extern "C" void kernel_launch(void* const* d_in, const int* in_sizes, int n_in,
                              void* d_out, int out_size, void* d_ws, size_t ws_size,
                              hipStream_t stream) {
    (void)in_sizes; (void)n_in; (void)out_size; (void)ws_size;

    const float* x    = (const float*)d_in[0];
    const float* Rr   = (const float*)d_in[1];
    const float* Rs   = (const float*)d_in[2];
    // d_in[3] = pstep (==2, hard-coded)
    const float* neW0 = (const float*)d_in[4];  const float* neb0 = (const float*)d_in[5];
    const float* neW1 = (const float*)d_in[6];  const float* neb1 = (const float*)d_in[7];
    const float* neW2 = (const float*)d_in[8];  const float* neb2 = (const float*)d_in[9];
    const float* eeW0 = (const float*)d_in[10]; const float* eeb0 = (const float*)d_in[11];
    const float* eeW1 = (const float*)d_in[12]; const float* eeb1 = (const float*)d_in[13];
    const float* eeW2 = (const float*)d_in[14]; const float* eeb2 = (const float*)d_in[15];
    const float* npW  = (const float*)d_in[16]; const float* npb  = (const float*)d_in[17];
    const float* epW  = (const float*)d_in[18]; const float* epb  = (const float*)d_in[19];
    const float* ppW0 = (const float*)d_in[20]; const float* ppb0 = (const float*)d_in[21];
    const float* ppW1 = (const float*)d_in[22]; const float* ppb1 = (const float*)d_in[23];
    const float* ppW2 = (const float*)d_in[24]; const float* ppb2 = (const float*)d_in[25];

    char* ws = (char*)d_ws;
    size_t off = 0;
    auto alloc = [&](size_t bytes) -> char* {
        char* p = ws + off;
        off += (bytes + 255) & ~(size_t)255;
        return p;
    };

    u16* f_neW0 = (u16*)alloc(32  * 128 * 2);
    u16* f_neW1 = (u16*)alloc(128 * 128 * 2);
    u16* f_neW2 = (u16*)alloc(128 * 128 * 2);
    u16* f_eeW0 = (u16*)alloc(64  * 128 * 2);
    u16* f_eeW1 = (u16*)alloc(128 * 128 * 2);
    u16* f_eeW2 = (u16*)alloc(128 * 128 * 2);
    u16* f_epW  = (u16*)alloc(384 * 128 * 2);
    u16* f_npW  = (u16*)alloc(256 * 128 * 2);
    u16* f_ppW0 = (u16*)alloc(256 * 128 * 2);
    u16* f_ppW1 = (u16*)alloc(128 * 128 * 2);
    int*   recv = (int*)alloc(BE * 4);
    int*   send = (int*)alloc(BE * 4);
    u16*   nT1  = (u16*)alloc((size_t)BN * 128 * 2);   // bf16 node temps
    u16*   nT2  = (u16*)alloc((size_t)BN * 128 * 2);
    float* nenc = (float*)alloc((size_t)BN * 128 * 4); // fp32 node tensors
    float* nef1 = (float*)alloc((size_t)BN * 128 * 4);
    float* nef2 = (float*)alloc((size_t)BN * 128 * 4);
    float* agg  = (float*)alloc((size_t)BN * 128 * 4);
    u16*   eA   = (u16*)alloc((size_t)BE * 128 * 2);   // bf16 edge ping-pong
    u16*   eB   = (u16*)alloc((size_t)BE * 128 * 2);

    // 1) weight fragment conversion (10 matrices, one launch)
    WPack P;
    P.d[0] = {neW0, f_neW0, 32};
    P.d[1] = {neW1, f_neW1, 128};
    P.d[2] = {neW2, f_neW2, 128};
    P.d[3] = {eeW0, f_eeW0, 64};
    P.d[4] = {eeW1, f_eeW1, 128};
    P.d[5] = {eeW2, f_eeW2, 128};
    P.d[6] = {epW,  f_epW,  384};
    P.d[7] = {npW,  f_npW,  256};
    P.d[8] = {ppW0, f_ppW0, 256};
    P.d[9] = {ppW1, f_ppW1, 128};
    k_wprep<<<dim3(192, 10), 256, 0, stream>>>(P);

    // 2) one-hot -> indices
    k_extract<<<(2 * BE) / 4, 256, 0, stream>>>(Rr, Rs, recv, send);

    SegD none = {nullptr, nullptr, 0, 0};
    auto seg = [](const void* p, int w, int f32, const int* idx = nullptr) {
        SegD s; s.p = p; s.idx = idx; s.f32 = f32; s.w = w; return s;
    };

    // 3) node encoder: x[4096,32] -> nT1 -> nT2 -> nenc (fp32)
    k_mfma<<<BN / 64, 256, 0, stream>>>(seg(x, 32, 1), none, none, 1, 1,
                                        f_neW0, neb0, nullptr, 0, nT1, nullptr);
    k_mfma<<<BN / 64, 256, 0, stream>>>(seg(nT1, 128, 0), none, none, 1, 4,
                                        f_neW1, neb1, nullptr, 0, nT2, nullptr);
    k_mfma<<<BN / 64, 256, 0, stream>>>(seg(nT2, 128, 0), none, none, 1, 4,
                                        f_neW2, neb2, nullptr, 2, nenc, nullptr);

    // 4) edge encoder: concat(x[recv], x[send]) [32768,64] -> eA -> eB -> eA(=eenc)
    k_mfma<<<BE / 64, 256, 0, stream>>>(seg(x, 32, 1, recv), seg(x, 32, 1, send), none, 2, 2,
                                        f_eeW0, eeb0, nullptr, 0, eA, nullptr);
    k_mfma<<<BE / 64, 256, 0, stream>>>(seg(eA, 128, 0), none, none, 1, 4,
                                        f_eeW1, eeb1, nullptr, 0, eB, nullptr);
    k_mfma<<<BE / 64, 256, 0, stream>>>(seg(eB, 128, 0), none, none, 1, 4,
                                        f_eeW2, eeb2, nullptr, 0, eA, nullptr);

    // 5) propagation steps (pstep = 2); eA == edge_encode throughout
    const float* eff = nenc;
    float* nout[2] = {nef1, nef2};
    for (int step = 0; step < 2; ++step) {
        k_zero<<<512, 256, 0, stream>>>(agg, BN * 128 / 4);
        // edge: relu(concat(eenc, eff[recv], eff[send]) @ epW + epb) -> scatter-add agg
        k_mfma<<<BE / 64, 256, 0, stream>>>(seg(eA, 128, 0), seg(eff, 128, 1, recv),
                                            seg(eff, 128, 1, send), 3, 12,
                                            f_epW, epb, nullptr, 1, agg, recv);
        // node: relu(concat(nenc, agg) @ npW + npb + eff) -> nout (fp32)
        k_mfma<<<BN / 64, 256, 0, stream>>>(seg(nenc, 128, 1), seg(agg, 128, 1), none, 2, 8,
                                            f_npW, npb, eff, 2, nout[step], nullptr);
        eff = nout[step];
    }

    // 6) predictor: concat(nenc, nef2) -> nT1 -> nT2 -> d_out
    k_mfma<<<BN / 64, 256, 0, stream>>>(seg(nenc, 128, 1), seg(nef2, 128, 1), none, 2, 8,
                                        f_ppW0, ppb0, nullptr, 0, nT1, nullptr);
    k_mfma<<<BN / 64, 256, 0, stream>>>(seg(nT1, 128, 0), none, none, 1, 4,
                                        f_ppW1, ppb1, nullptr, 0, nT2, nullptr);
    k_final<<<BN / 4, 256, 0, stream>>>(nT2, ppW2, ppb2, (float*)d_out);
}

// Round 3
// 393.908 us; speedup vs baseline: 1.2810x; 1.2810x over previous
//
#include <hip/hip_runtime.h>
#include <hip/hip_bf16.h>

// PropNet on MI355X — fp32 in/out, bf16 MFMA compute, fused row-local layers.
// B=4, N=1024, E=8192, NF_IN=32, H=128, NF_OUT=3, pstep=2 (fixed).
//
// Launches (9): k_wprep(+agg zero), k_extract, k_node3, k_edge3,
//               [k_eprop, k_nprop]x2, k_pred.
// All GEMM kernels: 64-thread (1-wave) blocks, 16 rows x 128 cols per wave,
// 16x16x32 bf16 MFMA. Multi-layer kernels relayout C->A through a per-wave
// LDS slab (16 x 132 fp32; padded stride -> <=2-way bank aliasing = free);
// no barriers needed (single wave per block).

typedef unsigned short u16;
typedef __attribute__((ext_vector_type(8))) __bf16 bf16x8;
typedef __attribute__((ext_vector_type(4))) float f32x4;

#define N_    1024
#define BN    4096      // B*N
#define BE    32768     // B*E
#define LOG_E 13
#define H_    128
#define LSTR  132       // LDS row stride (floats)

__device__ __forceinline__ u16 f2bf(float f) {
    __bf16 h = (__bf16)f;
    return __builtin_bit_cast(u16, h);
}

__device__ __forceinline__ bf16x8 cvt8(float4 f0, float4 f1) {
    bf16x8 a;
    a[0] = (__bf16)f0.x; a[1] = (__bf16)f0.y; a[2] = (__bf16)f0.z; a[3] = (__bf16)f0.w;
    a[4] = (__bf16)f1.x; a[5] = (__bf16)f1.y; a[6] = (__bf16)f1.z; a[7] = (__bf16)f1.w;
    return a;
}

// A-fragment (8 contiguous k) from fp32 global/LDS pointer (32B-aligned).
__device__ __forceinline__ bf16x8 a_from_f32(const float* p) {
    float4 f0 = *(const float4*)p;
    float4 f1 = *(const float4*)(p + 4);
    return cvt8(f0, f1);
}

// A-fragment from the per-wave LDS tile for K-chunk c.
__device__ __forceinline__ bf16x8 a_from_lds(const float* lds, int m, int quad, int c) {
    return a_from_f32(lds + m * LSTR + c * 32 + quad * 8);
}

// One K=32 chunk against all 8 column-tiles of a 128-wide weight.
__device__ __forceinline__ void mm8(const u16* __restrict__ Wf, int c, bf16x8 a,
                                    f32x4* acc, int lane) {
    const u16* wp = Wf + ((size_t)c * 8) * 64 * 8;
    #pragma unroll
    for (int nt = 0; nt < 8; ++nt) {
        bf16x8 bw = *(const bf16x8*)(wp + (size_t)(nt * 64 + lane) * 8);
        acc[nt] = __builtin_amdgcn_mfma_f32_16x16x32_bf16(a, bw, acc[nt], 0, 0, 0);
    }
}

__device__ __forceinline__ void zacc(f32x4* acc) {
    #pragma unroll
    for (int t = 0; t < 8; ++t) acc[t] = (f32x4){0.f, 0.f, 0.f, 0.f};
}

// bias + ReLU epilogue into the LDS tile (C-layout scatter; conflict-free phases).
__device__ __forceinline__ void epi_to_lds(float* lds, const f32x4* acc,
                                           const float* __restrict__ bias,
                                           int quad, int m) {
    #pragma unroll
    for (int nt = 0; nt < 8; ++nt) {
        float bv = bias[nt * 16 + m];
        #pragma unroll
        for (int i = 0; i < 4; ++i)
            lds[(quad * 4 + i) * LSTR + nt * 16 + m] = fmaxf(acc[nt][i] + bv, 0.f);
    }
}

// ---------------------------------------------------------------------------
// Weight permutation into bf16 B-fragment order; grid.y==10 zeroes agg.
// ---------------------------------------------------------------------------
struct WDesc { const float* src; u16* dst; int K; };
struct WPack { WDesc d[10]; };

__global__ __launch_bounds__(256) void k_wprep(WPack P, float* __restrict__ agg) {
    if (blockIdx.y == 10) {
        int i = blockIdx.x * 256 + threadIdx.x;          // 49152 threads
        for (int t = i; t < BN * H_ / 4; t += 192 * 256)
            ((float4*)agg)[t] = make_float4(0.f, 0.f, 0.f, 0.f);
        return;
    }
    WDesc d = P.d[blockIdx.y];
    int i = blockIdx.x * 256 + threadIdx.x;
    if (i >= d.K * 128) return;
    int j    = i & 7;
    int lane = (i >> 3) & 63;
    int nt   = (i >> 9) & 7;
    int c    = i >> 12;
    int k = c * 32 + (lane >> 4) * 8 + j;
    int n = nt * 16 + (lane & 15);
    d.dst[i] = f2bf(d.src[k * 128 + n]);
}

// ---------------------------------------------------------------------------
// fp32 one-hot -> index. One wave per row; early exit; defensive default 0.
// ---------------------------------------------------------------------------
__global__ __launch_bounds__(256) void k_extract(const float* __restrict__ Rr,
                                                 const float* __restrict__ Rs,
                                                 int* __restrict__ recv,
                                                 int* __restrict__ send) {
    int wave = threadIdx.x >> 6, lane = threadIdx.x & 63;
    int g = blockIdx.x * 4 + wave;           // < 2*BE
    const float* src;
    int* dst;
    if (g < BE) { src = Rr + (size_t)g * N_;        dst = recv + g; }
    else        { src = Rs + (size_t)(g - BE) * N_; dst = send + (g - BE); }
    int idx = 0;
    bool done = false;
    #pragma unroll
    for (int it = 0; it < 4; ++it) {
        if (!done) {
            int base = it * 256 + lane * 4;
            float4 v = *(const float4*)(src + base);
            int found = -1;
            if      (v.x != 0.f) found = base;
            else if (v.y != 0.f) found = base + 1;
            else if (v.z != 0.f) found = base + 2;
            else if (v.w != 0.f) found = base + 3;
            unsigned long long msk = __ballot(found >= 0);
            if (msk) {
                int sl = __ffsll((long long)msk) - 1;
                idx = __shfl(found, sl, 64);
                done = true;
            }
        }
    }
    if (lane == 0) *dst = idx;
}

// ---------------------------------------------------------------------------
// Node encoder: 3 fused layers, x[4096,32] -> nenc[4096,128] fp32.
// ---------------------------------------------------------------------------
__global__ __launch_bounds__(64) void k_node3(
    const float* __restrict__ x,
    const u16* __restrict__ W0, const float* __restrict__ b0,
    const u16* __restrict__ W1, const float* __restrict__ b1,
    const u16* __restrict__ W2, const float* __restrict__ b2,
    float* __restrict__ nenc)
{
    __shared__ float lds[2][16 * LSTR];
    int lane = threadIdx.x, m = lane & 15, quad = lane >> 4;
    int row16 = blockIdx.x * 16;
    f32x4 acc[8];

    zacc(acc);
    mm8(W0, 0, a_from_f32(x + (size_t)(row16 + m) * 32 + quad * 8), acc, lane);
    epi_to_lds(lds[0], acc, b0, quad, m);

    zacc(acc);
    #pragma unroll
    for (int c = 0; c < 4; ++c) mm8(W1, c, a_from_lds(lds[0], m, quad, c), acc, lane);
    epi_to_lds(lds[1], acc, b1, quad, m);

    zacc(acc);
    #pragma unroll
    for (int c = 0; c < 4; ++c) mm8(W2, c, a_from_lds(lds[1], m, quad, c), acc, lane);
    epi_to_lds(lds[0], acc, b2, quad, m);

    // coalesced fp32 store of the 16x128 tile
    #pragma unroll
    for (int t = 0; t < 32; ++t) {
        int flat = t * 64 + lane;
        int r = flat >> 7, col = flat & 127;
        nenc[(size_t)(row16 + r) * H_ + col] = lds[0][r * LSTR + col];
    }
}

// ---------------------------------------------------------------------------
// Edge encoder: 3 fused layers, concat(x[recv],x[send])[32768,64] -> eenc bf16.
// ---------------------------------------------------------------------------
__global__ __launch_bounds__(64) void k_edge3(
    const float* __restrict__ x,
    const int* __restrict__ recv, const int* __restrict__ send,
    const u16* __restrict__ W0, const float* __restrict__ b0,
    const u16* __restrict__ W1, const float* __restrict__ b1,
    const u16* __restrict__ W2, const float* __restrict__ b2,
    u16* __restrict__ eenc)
{
    __shared__ float lds[2][16 * LSTR];
    int lane = threadIdx.x, m = lane & 15, quad = lane >> 4;
    int row16 = blockIdx.x * 16;
    int e = row16 + m, b = e >> LOG_E;
    long rr = (long)b * N_ + recv[e];
    long rs = (long)b * N_ + send[e];
    f32x4 acc[8];

    zacc(acc);
    mm8(W0, 0, a_from_f32(x + rr * 32 + quad * 8), acc, lane);
    mm8(W0, 1, a_from_f32(x + rs * 32 + quad * 8), acc, lane);
    epi_to_lds(lds[0], acc, b0, quad, m);

    zacc(acc);
    #pragma unroll
    for (int c = 0; c < 4; ++c) mm8(W1, c, a_from_lds(lds[0], m, quad, c), acc, lane);
    epi_to_lds(lds[1], acc, b1, quad, m);

    zacc(acc);
    #pragma unroll
    for (int c = 0; c < 4; ++c) mm8(W2, c, a_from_lds(lds[1], m, quad, c), acc, lane);
    epi_to_lds(lds[0], acc, b2, quad, m);

    // coalesced bf16 store (paired)
    #pragma unroll
    for (int t = 0; t < 16; ++t) {
        int r = t, col = lane * 2;
        u16 lo = f2bf(lds[0][r * LSTR + col]);
        u16 hi = f2bf(lds[0][r * LSTR + col + 1]);
        *(unsigned*)(eenc + (size_t)(row16 + r) * H_ + col) =
            (unsigned)lo | ((unsigned)hi << 16);
    }
}

// ---------------------------------------------------------------------------
// Prop edge layer: relu(concat(eenc, eff[recv], eff[send]) @ epW + epb)
// fused scatter-add into fp32 agg.
// ---------------------------------------------------------------------------
__global__ __launch_bounds__(64) void k_eprop(
    const u16* __restrict__ eenc, const float* __restrict__ eff,
    const int* __restrict__ recv, const int* __restrict__ send,
    const u16* __restrict__ Wf, const float* __restrict__ bias,
    float* __restrict__ agg)
{
    int lane = threadIdx.x, m = lane & 15, quad = lane >> 4;
    int row16 = blockIdx.x * 16;
    int e = row16 + m, b = e >> LOG_E;
    long rr = (long)b * N_ + recv[e];
    long rs = (long)b * N_ + send[e];
    f32x4 acc[8];
    zacc(acc);

    #pragma unroll
    for (int c = 0; c < 4; ++c)
        mm8(Wf, c, *(const bf16x8*)(eenc + (size_t)e * H_ + c * 32 + quad * 8), acc, lane);
    #pragma unroll
    for (int c = 0; c < 4; ++c)
        mm8(Wf, 4 + c, a_from_f32(eff + rr * H_ + c * 32 + quad * 8), acc, lane);
    #pragma unroll
    for (int c = 0; c < 4; ++c)
        mm8(Wf, 8 + c, a_from_f32(eff + rs * H_ + c * 32 + quad * 8), acc, lane);

    // scatter-add epilogue: rows quad*4+i, receiver node from recv[]
    size_t tgt[4];
    #pragma unroll
    for (int i = 0; i < 4; ++i) {
        int r = row16 + quad * 4 + i;
        tgt[i] = ((size_t)(r >> LOG_E) * N_ + recv[r]) * H_;
    }
    #pragma unroll
    for (int nt = 0; nt < 8; ++nt) {
        int col = nt * 16 + m;
        float bv = bias[col];
        #pragma unroll
        for (int i = 0; i < 4; ++i)
            atomicAdd(agg + tgt[i] + col, fmaxf(acc[nt][i] + bv, 0.f));
    }
}

// ---------------------------------------------------------------------------
// Prop node layer: relu(concat(nenc, agg) @ npW + npb + eff) -> nout,
// then re-zero agg rows for the next step.
// ---------------------------------------------------------------------------
__global__ __launch_bounds__(64) void k_nprop(
    const float* __restrict__ nenc, float* __restrict__ agg,
    const float* __restrict__ eff,
    const u16* __restrict__ Wf, const float* __restrict__ bias,
    float* __restrict__ nout)
{
    int lane = threadIdx.x, m = lane & 15, quad = lane >> 4;
    int row16 = blockIdx.x * 16;
    int row = row16 + m;
    f32x4 acc[8];
    zacc(acc);

    #pragma unroll
    for (int c = 0; c < 4; ++c)
        mm8(Wf, c, a_from_f32(nenc + (size_t)row * H_ + c * 32 + quad * 8), acc, lane);
    #pragma unroll
    for (int c = 0; c < 4; ++c)
        mm8(Wf, 4 + c, a_from_f32(agg + (size_t)row * H_ + c * 32 + quad * 8), acc, lane);

    #pragma unroll
    for (int nt = 0; nt < 8; ++nt) {
        int col = nt * 16 + m;
        float bv = bias[col];
        #pragma unroll
        for (int i = 0; i < 4; ++i) {
            int r = row16 + quad * 4 + i;
            float v = fmaxf(acc[nt][i] + bv + eff[(size_t)r * H_ + col], 0.f);
            nout[(size_t)r * H_ + col] = v;
            agg[(size_t)r * H_ + col] = 0.f;   // re-zero for next prop step
        }
    }
}

// ---------------------------------------------------------------------------
// Predictor: 2 fused GEMM layers + [128,3] head -> fp32 d_out.
// ---------------------------------------------------------------------------
__global__ __launch_bounds__(64) void k_pred(
    const float* __restrict__ nenc, const float* __restrict__ eff,
    const u16* __restrict__ W0, const float* __restrict__ b0,
    const u16* __restrict__ W1, const float* __restrict__ b1,
    const float* __restrict__ W2, const float* __restrict__ b2,
    float* __restrict__ out)
{
    __shared__ float lds[2][16 * LSTR];
    int lane = threadIdx.x, m = lane & 15, quad = lane >> 4;
    int row16 = blockIdx.x * 16;
    int row = row16 + m;
    f32x4 acc[8];

    zacc(acc);
    #pragma unroll
    for (int c = 0; c < 4; ++c)
        mm8(W0, c, a_from_f32(nenc + (size_t)row * H_ + c * 32 + quad * 8), acc, lane);
    #pragma unroll
    for (int c = 0; c < 4; ++c)
        mm8(W0, 4 + c, a_from_f32(eff + (size_t)row * H_ + c * 32 + quad * 8), acc, lane);
    epi_to_lds(lds[0], acc, b0, quad, m);

    zacc(acc);
    #pragma unroll
    for (int c = 0; c < 4; ++c) mm8(W1, c, a_from_lds(lds[0], m, quad, c), acc, lane);
    epi_to_lds(lds[1], acc, b1, quad, m);

    // head: out[r,col] = p2[r,:] . W2[:,col] + b2[col]
    int r = lane & 15, col = lane >> 4;
    if (col < 3) {
        float s = 0.f;
        #pragma unroll 8
        for (int k = 0; k < 128; ++k)
            s += lds[1][r * LSTR + k] * W2[k * 3 + col];
        out[(size_t)(row16 + r) * 3 + col] = s + b2[col];
    }
}

// ---------------------------------------------------------------------------
extern "C" void kernel_launch(void* const* d_in, const int* in_sizes, int n_in,
                              void* d_out, int out_size, void* d_ws, size_t ws_size,
                              hipStream_t stream) {
    (void)in_sizes; (void)n_in; (void)out_size; (void)ws_size;

    const float* x    = (const float*)d_in[0];
    const float* Rr   = (const float*)d_in[1];
    const float* Rs   = (const float*)d_in[2];
    // d_in[3] = pstep (==2, hard-coded)
    const float* neW0 = (const float*)d_in[4];  const float* neb0 = (const float*)d_in[5];
    const float* neW1 = (const float*)d_in[6];  const float* neb1 = (const float*)d_in[7];
    const float* neW2 = (const float*)d_in[8];  const float* neb2 = (const float*)d_in[9];
    const float* eeW0 = (const float*)d_in[10]; const float* eeb0 = (const float*)d_in[11];
    const float* eeW1 = (const float*)d_in[12]; const float* eeb1 = (const float*)d_in[13];
    const float* eeW2 = (const float*)d_in[14]; const float* eeb2 = (const float*)d_in[15];
    const float* npW  = (const float*)d_in[16]; const float* npb  = (const float*)d_in[17];
    const float* epW  = (const float*)d_in[18]; const float* epb  = (const float*)d_in[19];
    const float* ppW0 = (const float*)d_in[20]; const float* ppb0 = (const float*)d_in[21];
    const float* ppW1 = (const float*)d_in[22]; const float* ppb1 = (const float*)d_in[23];
    const float* ppW2 = (const float*)d_in[24]; const float* ppb2 = (const float*)d_in[25];

    char* ws = (char*)d_ws;
    size_t off = 0;
    auto alloc = [&](size_t bytes) -> char* {
        char* p = ws + off;
        off += (bytes + 255) & ~(size_t)255;
        return p;
    };

    u16* f_neW0 = (u16*)alloc(32  * 128 * 2);
    u16* f_neW1 = (u16*)alloc(128 * 128 * 2);
    u16* f_neW2 = (u16*)alloc(128 * 128 * 2);
    u16* f_eeW0 = (u16*)alloc(64  * 128 * 2);
    u16* f_eeW1 = (u16*)alloc(128 * 128 * 2);
    u16* f_eeW2 = (u16*)alloc(128 * 128 * 2);
    u16* f_epW  = (u16*)alloc(384 * 128 * 2);
    u16* f_npW  = (u16*)alloc(256 * 128 * 2);
    u16* f_ppW0 = (u16*)alloc(256 * 128 * 2);
    u16* f_ppW1 = (u16*)alloc(128 * 128 * 2);
    int*   recv = (int*)alloc(BE * 4);
    int*   send = (int*)alloc(BE * 4);
    float* nenc = (float*)alloc((size_t)BN * H_ * 4);
    float* nef1 = (float*)alloc((size_t)BN * H_ * 4);
    float* nef2 = (float*)alloc((size_t)BN * H_ * 4);
    float* agg  = (float*)alloc((size_t)BN * H_ * 4);
    u16*   eenc = (u16*)alloc((size_t)BE * H_ * 2);

    // 1) weight fragment conversion + agg zero (one launch)
    WPack P;
    P.d[0] = {neW0, f_neW0, 32};
    P.d[1] = {neW1, f_neW1, 128};
    P.d[2] = {neW2, f_neW2, 128};
    P.d[3] = {eeW0, f_eeW0, 64};
    P.d[4] = {eeW1, f_eeW1, 128};
    P.d[5] = {eeW2, f_eeW2, 128};
    P.d[6] = {epW,  f_epW,  384};
    P.d[7] = {npW,  f_npW,  256};
    P.d[8] = {ppW0, f_ppW0, 256};
    P.d[9] = {ppW1, f_ppW1, 128};
    k_wprep<<<dim3(192, 11), 256, 0, stream>>>(P, agg);

    // 2) one-hot -> indices
    k_extract<<<(2 * BE) / 4, 256, 0, stream>>>(Rr, Rs, recv, send);

    // 3) fused encoders
    k_node3<<<BN / 16, 64, 0, stream>>>(x, f_neW0, neb0, f_neW1, neb1, f_neW2, neb2, nenc);
    k_edge3<<<BE / 16, 64, 0, stream>>>(x, recv, send,
                                        f_eeW0, eeb0, f_eeW1, eeb1, f_eeW2, eeb2, eenc);

    // 4) propagation steps (pstep = 2)
    k_eprop<<<BE / 16, 64, 0, stream>>>(eenc, nenc, recv, send, f_epW, epb, agg);
    k_nprop<<<BN / 16, 64, 0, stream>>>(nenc, agg, nenc, f_npW, npb, nef1);
    k_eprop<<<BE / 16, 64, 0, stream>>>(eenc, nef1, recv, send, f_epW, epb, agg);
    k_nprop<<<BN / 16, 64, 0, stream>>>(nenc, agg, nef1, f_npW, npb, nef2);

    // 5) predictor
    k_pred<<<BN / 16, 64, 0, stream>>>(nenc, nef2, f_ppW0, ppb0, f_ppW1, ppb1,
                                       ppW2, ppb2, (float*)d_out);
}